// Round 4
// baseline (347.271 us; speedup 1.0000x reference)
//
#include <hip/hip_runtime.h>
#include <hip/hip_bf16.h>

// DynamicFilter fused, R18 = persistent tile over batch axis.
//
// R17 post-mortem: waves_per_eu(8) forced VGPR=32 -> spills (WRITE_SIZE
// 8192->10046 KB) + conv2 2-row rolling lost reuse (1.5x LDS reads) -> 146us.
// Occupancy experiment confounded; reverted to 256thr/4-wave structure.
// Evidence so far: R13/R15/R16 (different VALU/LDS mixes) all ~106us, HBM 5%,
// no pipe >44% -> the invariant is per-tile fixed cost: 8192 short blocks x
// (stage latency + setup + barrier convoys + ramp) in 8 dispatch rounds.
// R18: grid 1024 blocks (4/CU exactly), each block keeps its (x,y) tile and
// loops batches b=0..7. Batch-invariant state (interior flag, staging
// offsets/masks incl. /24 divisions, bfr, t0o, biases, epilogue consts)
// computed ONCE. Next batch's halo prefetched into 6 regs/thread right after
// stage barrier -> HBM latency hides under conv1+conv2. Conv1 write-back
// fused per-m (R17-verified, live acc 8), b1/b2 folded into MFMA C-init
// (R17-verified). Memory layouts identical to R16 (PXS=40, 4-row rolling
// conv2) to isolate the persistence effect.
//
// LDS: xs0f 2.3K + pxc 2.3K + hs 32K = 36.6KB -> 4 blocks/CU.
// d_ws: w1c bf16 [32ch][64k] @0 (k>=50 zero), w2t bf16 [25tap][16f][32chpos]
// @4096 (f>=9 zero; chpos 2i->ch i, 2i+1->ch 16+i).

typedef __attribute__((ext_vector_type(8))) short bf16x8;
typedef __attribute__((ext_vector_type(4))) float f32x4;

#define HH 512
#define WW 512
#define TILE 16
#define XS_H 24
#define XS_W 24
#define XS_N (XS_H * XS_W)     // 576
#define HS_R 20
#define HS_C 20
#define PXS 40                 // shorts per px in hs (80B stride)

__device__ __forceinline__ unsigned short f2bf(float x) {
    union { float f; unsigned int u; } v; v.f = x;
    unsigned int u = v.u;
    u += 0x7FFFu + ((u >> 16) & 1u);   // round-to-nearest-even
    return (unsigned short)(u >> 16);
}

__device__ __forceinline__ unsigned int pack_bf2(float a, float b) {
    __hip_bfloat162 h2 = __float22bfloat162_rn(make_float2(a, b));
    union { __hip_bfloat162 h; unsigned int u; } cv; cv.h = h2;
    return cv.u;
}

__device__ __forceinline__ bf16x8 dw4_to_frag(unsigned int d0, unsigned int d1,
                                              unsigned int d2, unsigned int d3) {
    union { unsigned int u[4]; bf16x8 f; } cv;
    cv.u[0] = d0; cv.u[1] = d1; cv.u[2] = d2; cv.u[3] = d3;
    return cv.f;
}

__global__ void dynfilt_prep(const float* __restrict__ w1,
                             const float* __restrict__ w2,
                             unsigned short* __restrict__ w1c,
                             unsigned short* __restrict__ w2t)
{
    int gid = blockIdx.x * 256 + threadIdx.x;   // 8192 threads
    // w1c[ch32][k64]: k = 2*tap + ci; k>=50 -> 0
    for (int i = gid; i < 32 * 64; i += 8192) {
        int ch = i >> 6, k = i & 63;
        int tap = k >> 1, ci = k & 1;
        w1c[i] = (k < 50) ? f2bf(w1[(ch * 2 + ci) * 25 + tap]) : (unsigned short)0;
    }
    // w2t[tap25][f16][chpos32]: chpos 2i -> ch i, 2i+1 -> ch 16+i; f>=9 zero
    for (int i = gid; i < 25 * 16 * 32; i += 8192) {
        int p = i & 31;
        int f = (i >> 5) & 15;
        int tap = i >> 9;   // 0..24
        int ch = (p & 1) * 16 + (p >> 1);
        w2t[i] = (f < 9) ? f2bf(w2[(f * 32 + ch) * 25 + tap]) : (unsigned short)0;
    }
}

// conv2 pass over tap-cols [TC0, TC0+NTC): rolling 4-row B-frag buffer.
// B-frag(row = wv*4 + i + tr, col = n + tc) shared across (i,tr) with equal
// i+tr; rows rotate through R[.&3]. All indices compile-time after unroll.
template<int TC0, int NTC>
__device__ __forceinline__ void conv2_pass(const unsigned short* hsp,
                                           const unsigned short* __restrict__ w2t,
                                           int wv, int n, int kg, f32x4* acc) {
    bf16x8 R[4][NTC];
    #pragma unroll
    for (int q = 0; q < 4; ++q)
        #pragma unroll
        for (int j = 0; j < NTC; ++j)
            R[q][j] = *(const bf16x8*)(hsp + ((wv * 4 + q) * HS_C + n + TC0 + j) * PXS + kg * 8);
    #pragma unroll
    for (int tr = 0; tr < 5; ++tr) {
        #pragma unroll
        for (int j = 0; j < NTC; ++j) {
            bf16x8 afr = *(const bf16x8*)(w2t + ((tr * 5 + TC0 + j) * 16 + n) * 32 + kg * 8);
            #pragma unroll
            for (int i = 0; i < 4; ++i)
                acc[i] = __builtin_amdgcn_mfma_f32_16x16x32_bf16(afr, R[(tr + i) & 3][j], acc[i], 0, 0, 0);
        }
        if (tr < 4) {
            #pragma unroll
            for (int j = 0; j < NTC; ++j)
                R[tr & 3][j] = *(const bf16x8*)(hsp + ((wv * 4 + tr + 4) * HS_C + n + TC0 + j) * PXS + kg * 8);
        }
    }
}

__global__
__attribute__((amdgpu_flat_work_group_size(256, 256), amdgpu_waves_per_eu(4)))
void dynfilt_main(const float* __restrict__ image,
                  const float* __restrict__ refer,
                  const float* __restrict__ b1,
                  const float* __restrict__ b2,
                  const unsigned short* __restrict__ w1c,
                  const unsigned short* __restrict__ w2t,
                  float* __restrict__ out)
{
    __shared__ float xs0f[XS_N];                // image fp32 (epilogue), flat
    __shared__ unsigned int pxc[XS_N];          // packed (bf16 img | bf16 ref)
    __shared__ __align__(16) unsigned short hs[HS_R * HS_C * PXS];

    const int t   = threadIdx.x;
    const int gx0 = blockIdx.x * TILE;
    const int gy0 = blockIdx.y * TILE;

    // whole halo (rows gy0-4..+19, cols gx0-4..+19) in-bounds?
    const bool interior = (gy0 >= 4) && (gy0 + XS_H - 4 <= HH) &&
                          (gx0 >= 4) && (gx0 + XS_W - 4 <= WW);

    // ---- batch-invariant staging offsets + masks (computed once) ----
    int  soff[3]; bool sval[3];
    #pragma unroll
    for (int k = 0; k < 3; ++k) {
        int idx = t + k * 256;
        int r = idx / XS_W, c = idx - (idx / XS_W) * XS_W;
        int gy = gy0 - 4 + r, gx = gx0 - 4 + c;
        bool inb = (idx < XS_N) & ((unsigned)gy < HH) & ((unsigned)gx < WW);
        soff[k] = inb ? (gy * WW + gx) : 0;
        sval[k] = inb;
    }

    const int lane = t & 63;
    const int wv   = t >> 6;
    const int n    = lane & 15;
    const int kg   = lane >> 4;

    // ---- conv1 B-frags (w1c global, L1-hot) ----
    bf16x8 bfr[2][2];
    #pragma unroll
    for (int nt = 0; nt < 2; ++nt)
        #pragma unroll
        for (int s = 0; s < 2; ++s)
            bfr[nt][s] = *(const bf16x8*)(w1c + (nt * 16 + n) * 64 + s * 32 + kg * 8);

    // ---- per-lane pxc dword offsets for the 8 gathered taps ----
    int t0o[4], t1o[4];
    unsigned int t1m[4];
    #pragma unroll
    for (int j = 0; j < 4; ++j) {
        int tap0 = kg * 4 + j;                       // 0..15, always valid
        t0o[j] = (tap0 / 5) * XS_W + tap0 % 5;
        int tap1 = 16 + kg * 4 + j;                  // valid iff <= 24
        int vld  = (tap1 <= 24) ? 1 : 0;
        int tc   = vld ? tap1 : 0;
        t1o[j] = (tc / 5) * XS_W + tc % 5;
        t1m[j] = vld ? 0xFFFFFFFFu : 0u;
    }

    // px = mt*16 + n raster start (pr0,pc0) over 20-wide h grid
    int px0 = wv * 16 + n;
    const int pr0 = px0 / 20, pc0 = px0 - (px0 / 20) * 20;

    const float bb0 = b1[n], bb1 = b1[16 + n];

    // ---- conv2 / epilogue constants (once) ----
    float b2r[4];
    int eo[4];
    #pragma unroll
    for (int r2 = 0; r2 < 4; ++r2) {
        int f = kg * 4 + r2;
        b2r[r2] = (f < 9) ? b2[f] : 0.f;
        int fy = f / 3, fx = f - fy * 3;
        eo[r2] = (fy + 3) * XS_W + fx + 3;
    }

    // ---- prefetch batch 0 halo into regs ----
    float pvI[3], pvR[3];
    #pragma unroll
    for (int k = 0; k < 3; ++k) {
        pvI[k] = sval[k] ? image[soff[k]] : 0.f;
        pvR[k] = sval[k] ? refer[soff[k]] : 0.f;
    }

    #pragma unroll 1
    for (int bb = 0; bb < 8; ++bb) {
        // ---- stage write from prefetch regs ----
        #pragma unroll
        for (int k = 0; k < 3; ++k) {
            int idx = t + k * 256;
            if (idx < XS_N) {
                xs0f[idx] = pvI[k];
                pxc[idx]  = pack_bf2(pvI[k], pvR[k]);
            }
        }
        __syncthreads();   // A: xs0f/pxc ready

        // ---- issue next batch's prefetch (hides under conv1+conv2) ----
        if (bb < 7) {
            const float* ibn = image + (size_t)(bb + 1) * (HH * WW);
            const float* rbn = refer + (size_t)(bb + 1) * (HH * WW);
            #pragma unroll
            for (int k = 0; k < 3; ++k) {
                pvI[k] = sval[k] ? ibn[soff[k]] : 0.f;
                pvR[k] = sval[k] ? rbn[soff[k]] : 0.f;
            }
        }

        // ---- conv1 GEMM + fused leaky+pack write to hs ----
        int pr = pr0, pc = pc0;
        if (interior) {
            unsigned short* hp0 = hs + (wv * 16 + kg * 4) * PXS + 2 * n;
            #pragma unroll
            for (int m = 0; m < 7; ++m) {
                int mt = m * 4 + wv;
                if (mt < 25) {   // wave-uniform guard
                    const unsigned int* base = pxc + (pr * XS_W + pc);
                    unsigned int a0d[4], a1d[4];
                    #pragma unroll
                    for (int j = 0; j < 4; ++j) a0d[j] = base[t0o[j]];
                    #pragma unroll
                    for (int j = 0; j < 4; ++j) a1d[j] = base[t1o[j]] & t1m[j];
                    bf16x8 a0 = dw4_to_frag(a0d[0], a0d[1], a0d[2], a0d[3]);
                    bf16x8 a1 = dw4_to_frag(a1d[0], a1d[1], a1d[2], a1d[3]);
                    f32x4 d0 = (f32x4){bb0, bb0, bb0, bb0};
                    f32x4 d1 = (f32x4){bb1, bb1, bb1, bb1};
                    d0 = __builtin_amdgcn_mfma_f32_16x16x32_bf16(a0, bfr[0][0], d0, 0, 0, 0);
                    d0 = __builtin_amdgcn_mfma_f32_16x16x32_bf16(a1, bfr[0][1], d0, 0, 0, 0);
                    d1 = __builtin_amdgcn_mfma_f32_16x16x32_bf16(a0, bfr[1][0], d1, 0, 0, 0);
                    d1 = __builtin_amdgcn_mfma_f32_16x16x32_bf16(a1, bfr[1][1], d1, 0, 0, 0);
                    #pragma unroll
                    for (int r = 0; r < 4; ++r) {
                        float h0 = fmaxf(d0[r], 0.1f * d0[r]);
                        float h1 = fmaxf(d1[r], 0.1f * d1[r]);
                        *(unsigned int*)(hp0 + (m * 64 + r) * PXS) = pack_bf2(h0, h1);
                    }
                }
                pc += 4; pr += 3;
                int w = (pc >= 20) ? 1 : 0;
                pc -= 20 * w; pr += w;
            }
        } else {
            #pragma unroll
            for (int m = 0; m < 7; ++m) {
                int mt = m * 4 + wv;
                if (mt < 25) {
                    const unsigned int* base = pxc + (pr * XS_W + pc);
                    unsigned int a0d[4], a1d[4];
                    #pragma unroll
                    for (int j = 0; j < 4; ++j) a0d[j] = base[t0o[j]];
                    #pragma unroll
                    for (int j = 0; j < 4; ++j) a1d[j] = base[t1o[j]] & t1m[j];
                    bf16x8 a0 = dw4_to_frag(a0d[0], a0d[1], a0d[2], a0d[3]);
                    bf16x8 a1 = dw4_to_frag(a1d[0], a1d[1], a1d[2], a1d[3]);
                    f32x4 d0 = (f32x4){bb0, bb0, bb0, bb0};
                    f32x4 d1 = (f32x4){bb1, bb1, bb1, bb1};
                    d0 = __builtin_amdgcn_mfma_f32_16x16x32_bf16(a0, bfr[0][0], d0, 0, 0, 0);
                    d0 = __builtin_amdgcn_mfma_f32_16x16x32_bf16(a1, bfr[0][1], d0, 0, 0, 0);
                    d1 = __builtin_amdgcn_mfma_f32_16x16x32_bf16(a0, bfr[1][0], d1, 0, 0, 0);
                    d1 = __builtin_amdgcn_mfma_f32_16x16x32_bf16(a1, bfr[1][1], d1, 0, 0, 0);
                    #pragma unroll
                    for (int r = 0; r < 4; ++r) {
                        int px = mt * 16 + kg * 4 + r;   // D row = (lane>>4)*4 + reg
                        int prr = px / HS_C, pcc = px - prr * HS_C;
                        int gy = gy0 - 2 + prr, gx = gx0 - 2 + pcc;
                        bool inb = ((unsigned)gy < HH) & ((unsigned)gx < WW);
                        float h0 = fmaxf(d0[r], 0.1f * d0[r]);
                        float h1 = fmaxf(d1[r], 0.1f * d1[r]);
                        if (!inb) { h0 = 0.f; h1 = 0.f; }
                        *(unsigned int*)(hs + px * PXS + 2 * n) = pack_bf2(h0, h1);
                    }
                }
                pc += 4; pr += 3;
                int w = (pc >= 20) ? 1 : 0;
                pc -= 20 * w; pr += w;
            }
        }
        __syncthreads();   // B: hs ready

        // ---- conv2: rolling-row MFMA GEMM, b2 folded into C-init ----
        f32x4 acc[4];
        #pragma unroll
        for (int i = 0; i < 4; ++i)
            acc[i] = (f32x4){b2r[0], b2r[1], b2r[2], b2r[3]};

        conv2_pass<0, 3>(hs, w2t, wv, n, kg, acc);
        conv2_pass<3, 2>(hs, w2t, wv, n, kg, acc);

        // ---- epilogue: out = sum_f filt_f * image[y+fy-1][x+fx-1] ----
        #pragma unroll
        for (int i = 0; i < 4; ++i) {
            int py = wv * 4 + i;
            float partial = 0.f;
            #pragma unroll
            for (int r2 = 0; r2 < 4; ++r2)
                partial += acc[i][r2] * xs0f[py * XS_W + n + eo[r2]];   // f>=9 term exact-zero
            partial += __shfl_down(partial, 16, 64);
            partial += __shfl_down(partial, 32, 64);
            if (lane < 16)
                out[((size_t)bb * HH + gy0 + py) * WW + gx0 + n] = partial;
        }
        __syncthreads();   // C: xs0f/pxc/hs free for next batch
    }
}

extern "C" void kernel_launch(void* const* d_in, const int* in_sizes, int n_in,
                              void* d_out, int out_size, void* d_ws, size_t ws_size,
                              hipStream_t stream) {
    const float* image = (const float*)d_in[0];
    const float* refer = (const float*)d_in[1];
    const float* w1    = (const float*)d_in[2];
    const float* b1    = (const float*)d_in[3];
    const float* w2    = (const float*)d_in[4];
    const float* b2    = (const float*)d_in[5];

    unsigned short* w1c = (unsigned short*)d_ws;                   // 4 KB
    unsigned short* w2t = (unsigned short*)((char*)d_ws + 4096);   // 25.6 KB
    // ws re-poisoned before every launch -> prep must (and does) run every call

    hipLaunchKernelGGL(dynfilt_prep, dim3(32), dim3(256), 0, stream, w1, w2, w1c, w2t);

    dim3 grid(WW / TILE, HH / TILE, 1);   // persistent over batch: 1024 blocks
    hipLaunchKernelGGL(dynfilt_main, grid, dim3(256), 0, stream,
                       image, refer, b1, b2, w1c, w2t, (float*)d_out);
}

// Round 5
// 167.877 us; speedup vs baseline: 2.0686x; 2.0686x over previous
//
#include <hip/hip_runtime.h>
#include <hip/hip_bf16.h>

// DynamicFilter fused, R19 = R18 (persistent tile over batch) minus spills.
//
// R18 post-mortem: persistence concept untested -- waves_per_eu(4) capped
// VGPR at 64 (empirical rule: cap ~= 256/waves_per_eu, NOT 512/n) while the
// batch loop needs ~110-120 -> 29 dwords spilled/filled per thread per iter
// (WRITE 8->242 MB, FETCH 32->667 MB, MfmaUtil 9%, 301us). Same mechanism
// invalidated R17. Fix, nothing else changed vs R18:
//  1. waves_per_eu(2) -> cap ~128; LDS (36.6KB) still limits to 4 blocks/CU
//     so the looser bound costs zero occupancy while VGPR<=128.
//  2. conv2 pass split <0,3>,<3,2> -> <0,2>,<2,2>,<4,1>: identical LDS reads
//     (40/lane), afr loads (25) and MFMA (100/wave); peak R-buffer 48->32
//     VGPR => register peak ~120 -> ~104, safely under 128.
// Predict: WRITE back to 8192KB exactly, FETCH ~32MB, VGPR 96-112; if
// persistence thesis holds, main 106 -> 75-85us. If 106 with clean counters,
// the per-tile-fixed-cost theory is falsified -> next round captures stall
// counters.
//
// LDS: xs0f 2.3K + pxc 2.3K + hs 32K = 36.6KB -> 4 blocks/CU.
// d_ws: w1c bf16 [32ch][64k] @0 (k>=50 zero), w2t bf16 [25tap][16f][32chpos]
// @4096 (f>=9 zero; chpos 2i->ch i, 2i+1->ch 16+i).

typedef __attribute__((ext_vector_type(8))) short bf16x8;
typedef __attribute__((ext_vector_type(4))) float f32x4;

#define HH 512
#define WW 512
#define TILE 16
#define XS_H 24
#define XS_W 24
#define XS_N (XS_H * XS_W)     // 576
#define HS_R 20
#define HS_C 20
#define PXS 40                 // shorts per px in hs (80B stride)

__device__ __forceinline__ unsigned short f2bf(float x) {
    union { float f; unsigned int u; } v; v.f = x;
    unsigned int u = v.u;
    u += 0x7FFFu + ((u >> 16) & 1u);   // round-to-nearest-even
    return (unsigned short)(u >> 16);
}

__device__ __forceinline__ unsigned int pack_bf2(float a, float b) {
    __hip_bfloat162 h2 = __float22bfloat162_rn(make_float2(a, b));
    union { __hip_bfloat162 h; unsigned int u; } cv; cv.h = h2;
    return cv.u;
}

__device__ __forceinline__ bf16x8 dw4_to_frag(unsigned int d0, unsigned int d1,
                                              unsigned int d2, unsigned int d3) {
    union { unsigned int u[4]; bf16x8 f; } cv;
    cv.u[0] = d0; cv.u[1] = d1; cv.u[2] = d2; cv.u[3] = d3;
    return cv.f;
}

__global__ void dynfilt_prep(const float* __restrict__ w1,
                             const float* __restrict__ w2,
                             unsigned short* __restrict__ w1c,
                             unsigned short* __restrict__ w2t)
{
    int gid = blockIdx.x * 256 + threadIdx.x;   // 8192 threads
    // w1c[ch32][k64]: k = 2*tap + ci; k>=50 -> 0
    for (int i = gid; i < 32 * 64; i += 8192) {
        int ch = i >> 6, k = i & 63;
        int tap = k >> 1, ci = k & 1;
        w1c[i] = (k < 50) ? f2bf(w1[(ch * 2 + ci) * 25 + tap]) : (unsigned short)0;
    }
    // w2t[tap25][f16][chpos32]: chpos 2i -> ch i, 2i+1 -> ch 16+i; f>=9 zero
    for (int i = gid; i < 25 * 16 * 32; i += 8192) {
        int p = i & 31;
        int f = (i >> 5) & 15;
        int tap = i >> 9;   // 0..24
        int ch = (p & 1) * 16 + (p >> 1);
        w2t[i] = (f < 9) ? f2bf(w2[(f * 32 + ch) * 25 + tap]) : (unsigned short)0;
    }
}

// conv2 pass over tap-cols [TC0, TC0+NTC): rolling 4-row B-frag buffer.
// B-frag(row = wv*4 + i + tr, col = n + tc) shared across (i,tr) with equal
// i+tr; rows rotate through R[.&3]. All indices compile-time after unroll.
template<int TC0, int NTC>
__device__ __forceinline__ void conv2_pass(const unsigned short* hsp,
                                           const unsigned short* __restrict__ w2t,
                                           int wv, int n, int kg, f32x4* acc) {
    bf16x8 R[4][NTC];
    #pragma unroll
    for (int q = 0; q < 4; ++q)
        #pragma unroll
        for (int j = 0; j < NTC; ++j)
            R[q][j] = *(const bf16x8*)(hsp + ((wv * 4 + q) * HS_C + n + TC0 + j) * PXS + kg * 8);
    #pragma unroll
    for (int tr = 0; tr < 5; ++tr) {
        #pragma unroll
        for (int j = 0; j < NTC; ++j) {
            bf16x8 afr = *(const bf16x8*)(w2t + ((tr * 5 + TC0 + j) * 16 + n) * 32 + kg * 8);
            #pragma unroll
            for (int i = 0; i < 4; ++i)
                acc[i] = __builtin_amdgcn_mfma_f32_16x16x32_bf16(afr, R[(tr + i) & 3][j], acc[i], 0, 0, 0);
        }
        if (tr < 4) {
            #pragma unroll
            for (int j = 0; j < NTC; ++j)
                R[tr & 3][j] = *(const bf16x8*)(hsp + ((wv * 4 + tr + 4) * HS_C + n + TC0 + j) * PXS + kg * 8);
        }
    }
}

__global__
__attribute__((amdgpu_flat_work_group_size(256, 256), amdgpu_waves_per_eu(2)))
void dynfilt_main(const float* __restrict__ image,
                  const float* __restrict__ refer,
                  const float* __restrict__ b1,
                  const float* __restrict__ b2,
                  const unsigned short* __restrict__ w1c,
                  const unsigned short* __restrict__ w2t,
                  float* __restrict__ out)
{
    __shared__ float xs0f[XS_N];                // image fp32 (epilogue), flat
    __shared__ unsigned int pxc[XS_N];          // packed (bf16 img | bf16 ref)
    __shared__ __align__(16) unsigned short hs[HS_R * HS_C * PXS];

    const int t   = threadIdx.x;
    const int gx0 = blockIdx.x * TILE;
    const int gy0 = blockIdx.y * TILE;

    // whole halo (rows gy0-4..+19, cols gx0-4..+19) in-bounds?
    const bool interior = (gy0 >= 4) && (gy0 + XS_H - 4 <= HH) &&
                          (gx0 >= 4) && (gx0 + XS_W - 4 <= WW);

    // ---- batch-invariant staging offsets + masks (computed once) ----
    int  soff[3]; bool sval[3];
    #pragma unroll
    for (int k = 0; k < 3; ++k) {
        int idx = t + k * 256;
        int r = idx / XS_W, c = idx - (idx / XS_W) * XS_W;
        int gy = gy0 - 4 + r, gx = gx0 - 4 + c;
        bool inb = (idx < XS_N) & ((unsigned)gy < HH) & ((unsigned)gx < WW);
        soff[k] = inb ? (gy * WW + gx) : 0;
        sval[k] = inb;
    }

    const int lane = t & 63;
    const int wv   = t >> 6;
    const int n    = lane & 15;
    const int kg   = lane >> 4;

    // ---- conv1 B-frags (w1c global, L1-hot) ----
    bf16x8 bfr[2][2];
    #pragma unroll
    for (int nt = 0; nt < 2; ++nt)
        #pragma unroll
        for (int s = 0; s < 2; ++s)
            bfr[nt][s] = *(const bf16x8*)(w1c + (nt * 16 + n) * 64 + s * 32 + kg * 8);

    // ---- per-lane pxc dword offsets for the 8 gathered taps ----
    int t0o[4], t1o[4];
    unsigned int t1m[4];
    #pragma unroll
    for (int j = 0; j < 4; ++j) {
        int tap0 = kg * 4 + j;                       // 0..15, always valid
        t0o[j] = (tap0 / 5) * XS_W + tap0 % 5;
        int tap1 = 16 + kg * 4 + j;                  // valid iff <= 24
        int vld  = (tap1 <= 24) ? 1 : 0;
        int tc   = vld ? tap1 : 0;
        t1o[j] = (tc / 5) * XS_W + tc % 5;
        t1m[j] = vld ? 0xFFFFFFFFu : 0u;
    }

    // px = mt*16 + n raster start (pr0,pc0) over 20-wide h grid
    int px0 = wv * 16 + n;
    const int pr0 = px0 / 20, pc0 = px0 - (px0 / 20) * 20;

    const float bb0 = b1[n], bb1 = b1[16 + n];

    // ---- conv2 / epilogue constants (once) ----
    float b2r[4];
    int eo[4];
    #pragma unroll
    for (int r2 = 0; r2 < 4; ++r2) {
        int f = kg * 4 + r2;
        b2r[r2] = (f < 9) ? b2[f] : 0.f;
        int fy = f / 3, fx = f - fy * 3;
        eo[r2] = (fy + 3) * XS_W + fx + 3;
    }

    // ---- prefetch batch 0 halo into regs ----
    float pvI[3], pvR[3];
    #pragma unroll
    for (int k = 0; k < 3; ++k) {
        pvI[k] = sval[k] ? image[soff[k]] : 0.f;
        pvR[k] = sval[k] ? refer[soff[k]] : 0.f;
    }

    #pragma unroll 1
    for (int bb = 0; bb < 8; ++bb) {
        // ---- stage write from prefetch regs ----
        #pragma unroll
        for (int k = 0; k < 3; ++k) {
            int idx = t + k * 256;
            if (idx < XS_N) {
                xs0f[idx] = pvI[k];
                pxc[idx]  = pack_bf2(pvI[k], pvR[k]);
            }
        }
        __syncthreads();   // A: xs0f/pxc ready

        // ---- issue next batch's prefetch (hides under conv1+conv2) ----
        if (bb < 7) {
            const float* ibn = image + (size_t)(bb + 1) * (HH * WW);
            const float* rbn = refer + (size_t)(bb + 1) * (HH * WW);
            #pragma unroll
            for (int k = 0; k < 3; ++k) {
                pvI[k] = sval[k] ? ibn[soff[k]] : 0.f;
                pvR[k] = sval[k] ? rbn[soff[k]] : 0.f;
            }
        }

        // ---- conv1 GEMM + fused leaky+pack write to hs ----
        int pr = pr0, pc = pc0;
        if (interior) {
            unsigned short* hp0 = hs + (wv * 16 + kg * 4) * PXS + 2 * n;
            #pragma unroll
            for (int m = 0; m < 7; ++m) {
                int mt = m * 4 + wv;
                if (mt < 25) {   // wave-uniform guard
                    const unsigned int* base = pxc + (pr * XS_W + pc);
                    unsigned int a0d[4], a1d[4];
                    #pragma unroll
                    for (int j = 0; j < 4; ++j) a0d[j] = base[t0o[j]];
                    #pragma unroll
                    for (int j = 0; j < 4; ++j) a1d[j] = base[t1o[j]] & t1m[j];
                    bf16x8 a0 = dw4_to_frag(a0d[0], a0d[1], a0d[2], a0d[3]);
                    bf16x8 a1 = dw4_to_frag(a1d[0], a1d[1], a1d[2], a1d[3]);
                    f32x4 d0 = (f32x4){bb0, bb0, bb0, bb0};
                    f32x4 d1 = (f32x4){bb1, bb1, bb1, bb1};
                    d0 = __builtin_amdgcn_mfma_f32_16x16x32_bf16(a0, bfr[0][0], d0, 0, 0, 0);
                    d0 = __builtin_amdgcn_mfma_f32_16x16x32_bf16(a1, bfr[0][1], d0, 0, 0, 0);
                    d1 = __builtin_amdgcn_mfma_f32_16x16x32_bf16(a0, bfr[1][0], d1, 0, 0, 0);
                    d1 = __builtin_amdgcn_mfma_f32_16x16x32_bf16(a1, bfr[1][1], d1, 0, 0, 0);
                    #pragma unroll
                    for (int r = 0; r < 4; ++r) {
                        float h0 = fmaxf(d0[r], 0.1f * d0[r]);
                        float h1 = fmaxf(d1[r], 0.1f * d1[r]);
                        *(unsigned int*)(hp0 + (m * 64 + r) * PXS) = pack_bf2(h0, h1);
                    }
                }
                pc += 4; pr += 3;
                int w = (pc >= 20) ? 1 : 0;
                pc -= 20 * w; pr += w;
            }
        } else {
            #pragma unroll
            for (int m = 0; m < 7; ++m) {
                int mt = m * 4 + wv;
                if (mt < 25) {
                    const unsigned int* base = pxc + (pr * XS_W + pc);
                    unsigned int a0d[4], a1d[4];
                    #pragma unroll
                    for (int j = 0; j < 4; ++j) a0d[j] = base[t0o[j]];
                    #pragma unroll
                    for (int j = 0; j < 4; ++j) a1d[j] = base[t1o[j]] & t1m[j];
                    bf16x8 a0 = dw4_to_frag(a0d[0], a0d[1], a0d[2], a0d[3]);
                    bf16x8 a1 = dw4_to_frag(a1d[0], a1d[1], a1d[2], a1d[3]);
                    f32x4 d0 = (f32x4){bb0, bb0, bb0, bb0};
                    f32x4 d1 = (f32x4){bb1, bb1, bb1, bb1};
                    d0 = __builtin_amdgcn_mfma_f32_16x16x32_bf16(a0, bfr[0][0], d0, 0, 0, 0);
                    d0 = __builtin_amdgcn_mfma_f32_16x16x32_bf16(a1, bfr[0][1], d0, 0, 0, 0);
                    d1 = __builtin_amdgcn_mfma_f32_16x16x32_bf16(a0, bfr[1][0], d1, 0, 0, 0);
                    d1 = __builtin_amdgcn_mfma_f32_16x16x32_bf16(a1, bfr[1][1], d1, 0, 0, 0);
                    #pragma unroll
                    for (int r = 0; r < 4; ++r) {
                        int px = mt * 16 + kg * 4 + r;   // D row = (lane>>4)*4 + reg
                        int prr = px / HS_C, pcc = px - prr * HS_C;
                        int gy = gy0 - 2 + prr, gx = gx0 - 2 + pcc;
                        bool inb = ((unsigned)gy < HH) & ((unsigned)gx < WW);
                        float h0 = fmaxf(d0[r], 0.1f * d0[r]);
                        float h1 = fmaxf(d1[r], 0.1f * d1[r]);
                        if (!inb) { h0 = 0.f; h1 = 0.f; }
                        *(unsigned int*)(hs + px * PXS + 2 * n) = pack_bf2(h0, h1);
                    }
                }
                pc += 4; pr += 3;
                int w = (pc >= 20) ? 1 : 0;
                pc -= 20 * w; pr += w;
            }
        }
        __syncthreads();   // B: hs ready

        // ---- conv2: rolling-row MFMA GEMM, b2 folded into C-init ----
        f32x4 acc[4];
        #pragma unroll
        for (int i = 0; i < 4; ++i)
            acc[i] = (f32x4){b2r[0], b2r[1], b2r[2], b2r[3]};

        conv2_pass<0, 2>(hs, w2t, wv, n, kg, acc);
        conv2_pass<2, 2>(hs, w2t, wv, n, kg, acc);
        conv2_pass<4, 1>(hs, w2t, wv, n, kg, acc);

        // ---- epilogue: out = sum_f filt_f * image[y+fy-1][x+fx-1] ----
        #pragma unroll
        for (int i = 0; i < 4; ++i) {
            int py = wv * 4 + i;
            float partial = 0.f;
            #pragma unroll
            for (int r2 = 0; r2 < 4; ++r2)
                partial += acc[i][r2] * xs0f[py * XS_W + n + eo[r2]];   // f>=9 term exact-zero
            partial += __shfl_down(partial, 16, 64);
            partial += __shfl_down(partial, 32, 64);
            if (lane < 16)
                out[((size_t)bb * HH + gy0 + py) * WW + gx0 + n] = partial;
        }
        __syncthreads();   // C: xs0f/pxc/hs free for next batch
    }
}

extern "C" void kernel_launch(void* const* d_in, const int* in_sizes, int n_in,
                              void* d_out, int out_size, void* d_ws, size_t ws_size,
                              hipStream_t stream) {
    const float* image = (const float*)d_in[0];
    const float* refer = (const float*)d_in[1];
    const float* w1    = (const float*)d_in[2];
    const float* b1    = (const float*)d_in[3];
    const float* w2    = (const float*)d_in[4];
    const float* b2    = (const float*)d_in[5];

    unsigned short* w1c = (unsigned short*)d_ws;                   // 4 KB
    unsigned short* w2t = (unsigned short*)((char*)d_ws + 4096);   // 25.6 KB
    // ws re-poisoned before every launch -> prep must (and does) run every call

    hipLaunchKernelGGL(dynfilt_prep, dim3(32), dim3(256), 0, stream, w1, w2, w1c, w2t);

    dim3 grid(WW / TILE, HH / TILE, 1);   // persistent over batch: 1024 blocks
    hipLaunchKernelGGL(dynfilt_main, grid, dim3(256), 0, stream,
                       image, refer, b1, b2, w1c, w2t, (float*)d_out);
}

// Round 6
// 153.907 us; speedup vs baseline: 2.2564x; 1.0908x over previous
//
#include <hip/hip_runtime.h>
#include <hip/hip_bf16.h>

// DynamicFilter fused, R20 = R19 (persistent tile) with conv2 register peak
// cut below the 128-VGPR cap.
//
// R19 post-mortem: spills reduced not eliminated (WRITE 43MB = 8.2 output +
// ~35 spill; VGPR pinned at cap 128, allocator wanted ~135+; occupancy 21%).
// Yet per-tile cost fell 13 -> 7.4us: persistence pays, pressure is the tax.
// R20 cuts conv2 peak: NTC=1 rolling (5 single-column passes) -> R[4][1]=16
// VGPR (-16), sval folded into soff sign sentinel (-3). Identical LDS reads
// (40/lane), afr loads (25), MFMA (100/wave); only FP tap order changes.
// Expected peak ~100-110 < 128 cap -> zero spill.
// Predict: VGPR ~108-118, WRITE exactly 8192KB, FETCH ~33MB, occupancy
// 35-45%, main 119 -> 80-90us. If VGPR=128 again: cut t0o/t1o next. If clean
// but >=105us: persistence neutral -> revert R16 + stall counters.
//
// LDS: xs0f 2.3K + pxc 2.3K + hs 32K = 36.6KB -> 4 blocks/CU.
// d_ws: w1c bf16 [32ch][64k] @0 (k>=50 zero), w2t bf16 [25tap][16f][32chpos]
// @4096 (f>=9 zero; chpos 2i->ch i, 2i+1->ch 16+i).

typedef __attribute__((ext_vector_type(8))) short bf16x8;
typedef __attribute__((ext_vector_type(4))) float f32x4;

#define HH 512
#define WW 512
#define TILE 16
#define XS_H 24
#define XS_W 24
#define XS_N (XS_H * XS_W)     // 576
#define HS_R 20
#define HS_C 20
#define PXS 40                 // shorts per px in hs (80B stride)

__device__ __forceinline__ unsigned short f2bf(float x) {
    union { float f; unsigned int u; } v; v.f = x;
    unsigned int u = v.u;
    u += 0x7FFFu + ((u >> 16) & 1u);   // round-to-nearest-even
    return (unsigned short)(u >> 16);
}

__device__ __forceinline__ unsigned int pack_bf2(float a, float b) {
    __hip_bfloat162 h2 = __float22bfloat162_rn(make_float2(a, b));
    union { __hip_bfloat162 h; unsigned int u; } cv; cv.h = h2;
    return cv.u;
}

__device__ __forceinline__ bf16x8 dw4_to_frag(unsigned int d0, unsigned int d1,
                                              unsigned int d2, unsigned int d3) {
    union { unsigned int u[4]; bf16x8 f; } cv;
    cv.u[0] = d0; cv.u[1] = d1; cv.u[2] = d2; cv.u[3] = d3;
    return cv.f;
}

__global__ void dynfilt_prep(const float* __restrict__ w1,
                             const float* __restrict__ w2,
                             unsigned short* __restrict__ w1c,
                             unsigned short* __restrict__ w2t)
{
    int gid = blockIdx.x * 256 + threadIdx.x;   // 8192 threads
    // w1c[ch32][k64]: k = 2*tap + ci; k>=50 -> 0
    for (int i = gid; i < 32 * 64; i += 8192) {
        int ch = i >> 6, k = i & 63;
        int tap = k >> 1, ci = k & 1;
        w1c[i] = (k < 50) ? f2bf(w1[(ch * 2 + ci) * 25 + tap]) : (unsigned short)0;
    }
    // w2t[tap25][f16][chpos32]: chpos 2i -> ch i, 2i+1 -> ch 16+i; f>=9 zero
    for (int i = gid; i < 25 * 16 * 32; i += 8192) {
        int p = i & 31;
        int f = (i >> 5) & 15;
        int tap = i >> 9;   // 0..24
        int ch = (p & 1) * 16 + (p >> 1);
        w2t[i] = (f < 9) ? f2bf(w2[(f * 32 + ch) * 25 + tap]) : (unsigned short)0;
    }
}

// conv2 pass over single tap-col TC0: rolling 4-row B-frag buffer.
// B-frag(row = wv*4 + i + tr, col = n + TC0) shared across (i,tr) with equal
// i+tr; rows rotate through R[.&3]. All indices compile-time after unroll.
template<int TC0>
__device__ __forceinline__ void conv2_pass(const unsigned short* hsp,
                                           const unsigned short* __restrict__ w2t,
                                           int wv, int n, int kg, f32x4* acc) {
    bf16x8 R[4];
    #pragma unroll
    for (int q = 0; q < 4; ++q)
        R[q] = *(const bf16x8*)(hsp + ((wv * 4 + q) * HS_C + n + TC0) * PXS + kg * 8);
    #pragma unroll
    for (int tr = 0; tr < 5; ++tr) {
        bf16x8 afr = *(const bf16x8*)(w2t + ((tr * 5 + TC0) * 16 + n) * 32 + kg * 8);
        #pragma unroll
        for (int i = 0; i < 4; ++i)
            acc[i] = __builtin_amdgcn_mfma_f32_16x16x32_bf16(afr, R[(tr + i) & 3], acc[i], 0, 0, 0);
        if (tr < 4)
            R[tr & 3] = *(const bf16x8*)(hsp + ((wv * 4 + tr + 4) * HS_C + n + TC0) * PXS + kg * 8);
    }
}

__global__
__attribute__((amdgpu_flat_work_group_size(256, 256), amdgpu_waves_per_eu(2)))
void dynfilt_main(const float* __restrict__ image,
                  const float* __restrict__ refer,
                  const float* __restrict__ b1,
                  const float* __restrict__ b2,
                  const unsigned short* __restrict__ w1c,
                  const unsigned short* __restrict__ w2t,
                  float* __restrict__ out)
{
    __shared__ float xs0f[XS_N];                // image fp32 (epilogue), flat
    __shared__ unsigned int pxc[XS_N];          // packed (bf16 img | bf16 ref)
    __shared__ __align__(16) unsigned short hs[HS_R * HS_C * PXS];

    const int t   = threadIdx.x;
    const int gx0 = blockIdx.x * TILE;
    const int gy0 = blockIdx.y * TILE;

    // whole halo (rows gy0-4..+19, cols gx0-4..+19) in-bounds?
    const bool interior = (gy0 >= 4) && (gy0 + XS_H - 4 <= HH) &&
                          (gx0 >= 4) && (gx0 + XS_W - 4 <= WW);

    // ---- batch-invariant staging offsets (sentinel -1 = skip) ----
    int soff[3];
    #pragma unroll
    for (int k = 0; k < 3; ++k) {
        int idx = t + k * 256;
        int r = idx / XS_W, c = idx - (idx / XS_W) * XS_W;
        int gy = gy0 - 4 + r, gx = gx0 - 4 + c;
        bool inb = (idx < XS_N) & ((unsigned)gy < HH) & ((unsigned)gx < WW);
        soff[k] = inb ? (gy * WW + gx) : -1;
    }

    const int lane = t & 63;
    const int wv   = t >> 6;
    const int n    = lane & 15;
    const int kg   = lane >> 4;

    // ---- conv1 B-frags (w1c global, L1-hot) ----
    bf16x8 bfr[2][2];
    #pragma unroll
    for (int nt = 0; nt < 2; ++nt)
        #pragma unroll
        for (int s = 0; s < 2; ++s)
            bfr[nt][s] = *(const bf16x8*)(w1c + (nt * 16 + n) * 64 + s * 32 + kg * 8);

    // ---- per-lane pxc dword offsets for the 8 gathered taps ----
    int t0o[4], t1o[4];
    unsigned int t1m[4];
    #pragma unroll
    for (int j = 0; j < 4; ++j) {
        int tap0 = kg * 4 + j;                       // 0..15, always valid
        t0o[j] = (tap0 / 5) * XS_W + tap0 % 5;
        int tap1 = 16 + kg * 4 + j;                  // valid iff <= 24
        int vld  = (tap1 <= 24) ? 1 : 0;
        int tc   = vld ? tap1 : 0;
        t1o[j] = (tc / 5) * XS_W + tc % 5;
        t1m[j] = vld ? 0xFFFFFFFFu : 0u;
    }

    // px = mt*16 + n raster start (pr0,pc0) over 20-wide h grid
    int px0 = wv * 16 + n;
    const int pr0 = px0 / 20, pc0 = px0 - (px0 / 20) * 20;

    const float bb0 = b1[n], bb1 = b1[16 + n];

    // ---- conv2 / epilogue constants (once) ----
    float b2r[4];
    int eo[4];
    #pragma unroll
    for (int r2 = 0; r2 < 4; ++r2) {
        int f = kg * 4 + r2;
        b2r[r2] = (f < 9) ? b2[f] : 0.f;
        int fy = f / 3, fx = f - fy * 3;
        eo[r2] = (fy + 3) * XS_W + fx + 3;
    }

    // ---- prefetch batch 0 halo into regs ----
    float pvI[3], pvR[3];
    #pragma unroll
    for (int k = 0; k < 3; ++k) {
        pvI[k] = 0.f; pvR[k] = 0.f;
        if (soff[k] >= 0) {
            pvI[k] = image[soff[k]];
            pvR[k] = refer[soff[k]];
        }
    }

    #pragma unroll 1
    for (int bb = 0; bb < 8; ++bb) {
        // ---- stage write from prefetch regs ----
        #pragma unroll
        for (int k = 0; k < 3; ++k) {
            int idx = t + k * 256;
            if (idx < XS_N) {
                xs0f[idx] = pvI[k];
                pxc[idx]  = pack_bf2(pvI[k], pvR[k]);
            }
        }
        __syncthreads();   // A: xs0f/pxc ready

        // ---- issue next batch's prefetch (hides under conv1+conv2) ----
        if (bb < 7) {
            const float* ibn = image + (size_t)(bb + 1) * (HH * WW);
            const float* rbn = refer + (size_t)(bb + 1) * (HH * WW);
            #pragma unroll
            for (int k = 0; k < 3; ++k) {
                pvI[k] = 0.f; pvR[k] = 0.f;
                if (soff[k] >= 0) {
                    pvI[k] = ibn[soff[k]];
                    pvR[k] = rbn[soff[k]];
                }
            }
        }

        // ---- conv1 GEMM + fused leaky+pack write to hs ----
        int pr = pr0, pc = pc0;
        if (interior) {
            unsigned short* hp0 = hs + (wv * 16 + kg * 4) * PXS + 2 * n;
            #pragma unroll
            for (int m = 0; m < 7; ++m) {
                int mt = m * 4 + wv;
                if (mt < 25) {   // wave-uniform guard
                    const unsigned int* base = pxc + (pr * XS_W + pc);
                    unsigned int a0d[4], a1d[4];
                    #pragma unroll
                    for (int j = 0; j < 4; ++j) a0d[j] = base[t0o[j]];
                    #pragma unroll
                    for (int j = 0; j < 4; ++j) a1d[j] = base[t1o[j]] & t1m[j];
                    bf16x8 a0 = dw4_to_frag(a0d[0], a0d[1], a0d[2], a0d[3]);
                    bf16x8 a1 = dw4_to_frag(a1d[0], a1d[1], a1d[2], a1d[3]);
                    f32x4 d0 = (f32x4){bb0, bb0, bb0, bb0};
                    f32x4 d1 = (f32x4){bb1, bb1, bb1, bb1};
                    d0 = __builtin_amdgcn_mfma_f32_16x16x32_bf16(a0, bfr[0][0], d0, 0, 0, 0);
                    d0 = __builtin_amdgcn_mfma_f32_16x16x32_bf16(a1, bfr[0][1], d0, 0, 0, 0);
                    d1 = __builtin_amdgcn_mfma_f32_16x16x32_bf16(a0, bfr[1][0], d1, 0, 0, 0);
                    d1 = __builtin_amdgcn_mfma_f32_16x16x32_bf16(a1, bfr[1][1], d1, 0, 0, 0);
                    #pragma unroll
                    for (int r = 0; r < 4; ++r) {
                        float h0 = fmaxf(d0[r], 0.1f * d0[r]);
                        float h1 = fmaxf(d1[r], 0.1f * d1[r]);
                        *(unsigned int*)(hp0 + (m * 64 + r) * PXS) = pack_bf2(h0, h1);
                    }
                }
                pc += 4; pr += 3;
                int w = (pc >= 20) ? 1 : 0;
                pc -= 20 * w; pr += w;
            }
        } else {
            #pragma unroll
            for (int m = 0; m < 7; ++m) {
                int mt = m * 4 + wv;
                if (mt < 25) {
                    const unsigned int* base = pxc + (pr * XS_W + pc);
                    unsigned int a0d[4], a1d[4];
                    #pragma unroll
                    for (int j = 0; j < 4; ++j) a0d[j] = base[t0o[j]];
                    #pragma unroll
                    for (int j = 0; j < 4; ++j) a1d[j] = base[t1o[j]] & t1m[j];
                    bf16x8 a0 = dw4_to_frag(a0d[0], a0d[1], a0d[2], a0d[3]);
                    bf16x8 a1 = dw4_to_frag(a1d[0], a1d[1], a1d[2], a1d[3]);
                    f32x4 d0 = (f32x4){bb0, bb0, bb0, bb0};
                    f32x4 d1 = (f32x4){bb1, bb1, bb1, bb1};
                    d0 = __builtin_amdgcn_mfma_f32_16x16x32_bf16(a0, bfr[0][0], d0, 0, 0, 0);
                    d0 = __builtin_amdgcn_mfma_f32_16x16x32_bf16(a1, bfr[0][1], d0, 0, 0, 0);
                    d1 = __builtin_amdgcn_mfma_f32_16x16x32_bf16(a0, bfr[1][0], d1, 0, 0, 0);
                    d1 = __builtin_amdgcn_mfma_f32_16x16x32_bf16(a1, bfr[1][1], d1, 0, 0, 0);
                    #pragma unroll
                    for (int r = 0; r < 4; ++r) {
                        int px = mt * 16 + kg * 4 + r;   // D row = (lane>>4)*4 + reg
                        int prr = px / HS_C, pcc = px - prr * HS_C;
                        int gy = gy0 - 2 + prr, gx = gx0 - 2 + pcc;
                        bool inb = ((unsigned)gy < HH) & ((unsigned)gx < WW);
                        float h0 = fmaxf(d0[r], 0.1f * d0[r]);
                        float h1 = fmaxf(d1[r], 0.1f * d1[r]);
                        if (!inb) { h0 = 0.f; h1 = 0.f; }
                        *(unsigned int*)(hs + px * PXS + 2 * n) = pack_bf2(h0, h1);
                    }
                }
                pc += 4; pr += 3;
                int w = (pc >= 20) ? 1 : 0;
                pc -= 20 * w; pr += w;
            }
        }
        __syncthreads();   // B: hs ready

        // ---- conv2: rolling-row MFMA GEMM (5 single-col passes), b2-init ----
        f32x4 acc[4];
        #pragma unroll
        for (int i = 0; i < 4; ++i)
            acc[i] = (f32x4){b2r[0], b2r[1], b2r[2], b2r[3]};

        conv2_pass<0>(hs, w2t, wv, n, kg, acc);
        conv2_pass<1>(hs, w2t, wv, n, kg, acc);
        conv2_pass<2>(hs, w2t, wv, n, kg, acc);
        conv2_pass<3>(hs, w2t, wv, n, kg, acc);
        conv2_pass<4>(hs, w2t, wv, n, kg, acc);

        // ---- epilogue: out = sum_f filt_f * image[y+fy-1][x+fx-1] ----
        #pragma unroll
        for (int i = 0; i < 4; ++i) {
            int py = wv * 4 + i;
            float partial = 0.f;
            #pragma unroll
            for (int r2 = 0; r2 < 4; ++r2)
                partial += acc[i][r2] * xs0f[py * XS_W + n + eo[r2]];   // f>=9 term exact-zero
            partial += __shfl_down(partial, 16, 64);
            partial += __shfl_down(partial, 32, 64);
            if (lane < 16)
                out[((size_t)bb * HH + gy0 + py) * WW + gx0 + n] = partial;
        }
        __syncthreads();   // C: xs0f/pxc/hs free for next batch
    }
}

extern "C" void kernel_launch(void* const* d_in, const int* in_sizes, int n_in,
                              void* d_out, int out_size, void* d_ws, size_t ws_size,
                              hipStream_t stream) {
    const float* image = (const float*)d_in[0];
    const float* refer = (const float*)d_in[1];
    const float* w1    = (const float*)d_in[2];
    const float* b1    = (const float*)d_in[3];
    const float* w2    = (const float*)d_in[4];
    const float* b2    = (const float*)d_in[5];

    unsigned short* w1c = (unsigned short*)d_ws;                   // 4 KB
    unsigned short* w2t = (unsigned short*)((char*)d_ws + 4096);   // 25.6 KB
    // ws re-poisoned before every launch -> prep must (and does) run every call

    hipLaunchKernelGGL(dynfilt_prep, dim3(32), dim3(256), 0, stream, w1, w2, w1c, w2t);

    dim3 grid(WW / TILE, HH / TILE, 1);   // persistent over batch: 1024 blocks
    hipLaunchKernelGGL(dynfilt_main, grid, dim3(256), 0, stream,
                       image, refer, b1, b2, w1c, w2t, (float*)d_out);
}